// Round 2
// baseline (296.342 us; speedup 1.0000x reference)
//
#include <hip/hip_runtime.h>
#include <hip/hip_bf16.h>

// irreps: 512x0e + 256x1o + 128x2e ; x,out: [16384, 1920] fp32, weight: 344064 fp32
// v2: whole-K A-tile staged in LDS once (ONE barrier per kernel, no per-step barriers),
// register-transpose staging for D>1 (ds_write_b128 only), barrier-free MFMA K-loop.

typedef float  f32x4  __attribute__((ext_vector_type(4)));
typedef short  bf16x8 __attribute__((ext_vector_type(8)));

#define ROWLEN 1920

__device__ __forceinline__ unsigned short f2bf(float f) {
    union { float f; unsigned int u; } c; c.f = f;
    unsigned int u = c.u;
    u += 0x7fffu + ((u >> 16) & 1u);   // round-to-nearest-even
    return (unsigned short)(u >> 16);
}

__global__ __launch_bounds__(256) void prep_weights(const float* __restrict__ w,
                                                    unsigned short* __restrict__ wt) {
    int g = blockIdx.x * 256 + threadIdx.x;
    if (g >= 344064) return;
    int base, sh;
    if      (g < 262144) { base = 0;      sh = 9; }   // mul=512
    else if (g < 327680) { base = 262144; sh = 8; }   // mul=256
    else                 { base = 327680; sh = 7; }   // mul=128
    int local = g - base;
    int u = local >> sh;
    int v = local & ((1 << sh) - 1);
    wt[base + (v << sh) + u] = f2bf(w[g]);   // Wt[v][u], K-contiguous
}

// Logical GEMM: C[(i,n), v] = sum_u x[n,u,i] * W[u,v]
template<int MUL, int D, int TN, int X_OFF, int WT_BASE>
__global__ __launch_bounds__(256) void seg_gemm(const float* __restrict__ x,
                                                const unsigned short* __restrict__ wt,
                                                float* __restrict__ out,
                                                float scale) {
    constexpr int NSTEP   = MUL / 32;      // MFMA K-steps
    constexpr int M_LOG   = TN * D;        // logical rows (mult of 16)
    constexpr int MT      = M_LOG / 16;
    constexpr int WAVE_NT = MUL / 64;      // 4 waves cover all MUL cols
    constexpr int STRIDE  = MUL + 8;       // shorts; keeps 16B alignment, benign banks
    constexpr int NUG     = MUL / 8;       // 8-u groups per row

    __shared__ unsigned short lds[M_LOG * STRIDE];

    const int tid  = threadIdx.x;
    const int wave = tid >> 6;
    const int lane = tid & 63;
    const int q    = lane >> 4;
    const int t16  = lane & 15;
    const int n0   = blockIdx.x * TN;

    const float* __restrict__ xblk = x + X_OFF + n0 * ROWLEN;
    const unsigned short* __restrict__ wblk = wt + WT_BASE;

    // ---- stage ENTIRE A tile: fp32 -> bf16, u-i transpose in registers, b128 LDS writes
    for (int idx = tid; idx < TN * NUG; idx += 256) {
        const int nl = idx / NUG;          // row in tile
        const int ug = idx % NUG;          // group of 8 consecutive u
        const float* src = xblk + nl * ROWLEN + ug * 8 * D;
        f32x4 v[2 * D];
#pragma unroll
        for (int j = 0; j < 2 * D; ++j) v[j] = *(const f32x4*)(src + 4 * j);
#pragma unroll
        for (int i = 0; i < D; ++i) {
            bf16x8 o;
#pragma unroll
            for (int t = 0; t < 8; ++t) {
                const int j = t * D + i;   // element (u=ug*8+t, comp i)
                o[t] = (short)f2bf(v[j >> 2][j & 3]);
            }
            *(bf16x8*)&lds[(i * TN + nl) * STRIDE + ug * 8] = o;
        }
    }
    __syncthreads();   // the only barrier

    f32x4 acc[MT][WAVE_NT];
#pragma unroll
    for (int a = 0; a < MT; ++a)
#pragma unroll
        for (int b = 0; b < WAVE_NT; ++b) acc[a][b] = (f32x4)0.0f;

    const int vbase = wave * (WAVE_NT * 16) + t16;

    // ---- barrier-free K loop: LDS A-frags + L2-resident B-frags -> MFMA
#pragma unroll
    for (int ks = 0; ks < NSTEP; ++ks) {
        const int u0 = ks * 32;
        bf16x8 afr[MT];
#pragma unroll
        for (int tm = 0; tm < MT; ++tm)
            afr[tm] = *(const bf16x8*)&lds[(16 * tm + t16) * STRIDE + u0 + q * 8];
#pragma unroll
        for (int tv = 0; tv < WAVE_NT; ++tv) {
            const bf16x8 bfr = *(const bf16x8*)&wblk[(vbase + tv * 16) * MUL + u0 + q * 8];
#pragma unroll
            for (int tm = 0; tm < MT; ++tm)
                acc[tm][tv] = __builtin_amdgcn_mfma_f32_16x16x32_bf16(afr[tm], bfr, acc[tm][tv], 0, 0, 0);
        }
    }

    // ---- epilogue: C/D layout col=lane&15, row=q*4+r ; apply 1/sqrt(mul)
#pragma unroll
    for (int tm = 0; tm < MT; ++tm) {
#pragma unroll
        for (int tv = 0; tv < WAVE_NT; ++tv) {
            const int v = vbase + tv * 16;
#pragma unroll
            for (int r = 0; r < 4; ++r) {
                const int rit = q * 4 + r;
                const int nl   = (D == 1) ? (16 * tm + rit) : rit;
                const int comp = (D == 1) ? 0 : tm;
                out[(n0 + nl) * ROWLEN + X_OFF + v * D + comp] = acc[tm][tv][r] * scale;
            }
        }
    }
}

extern "C" void kernel_launch(void* const* d_in, const int* in_sizes, int n_in,
                              void* d_out, int out_size, void* d_ws, size_t ws_size,
                              hipStream_t stream) {
    const float* x = (const float*)d_in[0];
    const float* w = (const float*)d_in[1];
    float* out = (float*)d_out;
    unsigned short* wt = (unsigned short*)d_ws;   // 344064 bf16 = 688 KB

    hipLaunchKernelGGL(prep_weights, dim3((344064 + 255) / 256), dim3(256), 0, stream, w, wt);

    // block0: mul=512, d=1, TN=32 -> 512 wgs; LDS 33.3 KB; per-wave 2x8 acc tiles
    hipLaunchKernelGGL((seg_gemm<512, 1, 32, 0, 0>),
                       dim3(16384 / 32), dim3(256), 0, stream, x, wt, out, 0.044194173824f);
    // block1: mul=256, d=3, TN=16 -> 1024 wgs; LDS 25.3 KB; per-wave 3x4 acc tiles
    hipLaunchKernelGGL((seg_gemm<256, 3, 16, 512, 262144>),
                       dim3(16384 / 16), dim3(256), 0, stream, x, wt, out, 0.0625f);
    // block2: mul=128, d=5, TN=16 -> 1024 wgs; LDS 21.8 KB; per-wave 5x2 acc tiles
    hipLaunchKernelGGL((seg_gemm<128, 5, 16, 1280, 327680>),
                       dim3(16384 / 16), dim3(256), 0, stream, x, wt, out, 0.088388347648f);
}